// Round 7
// baseline (300.444 us; speedup 1.0000x reference)
//
#include <hip/hip_runtime.h>
#include <hip/hip_bf16.h>
#include <math.h>

#define Bb 4
#define Ss 512
#define Dd 512
#define Hh 2048
#define Ee 8
#define TOKENS 2048
#define CAP 2048

typedef __attribute__((ext_vector_type(8))) _Float16 f16x8;
typedef __attribute__((ext_vector_type(4))) _Float16 f16x4;
typedef __attribute__((ext_vector_type(4))) float f32x4;

// ---------------- ws layout (bytes) ----------------
#define WS_CNT   0
#define WS_OFFS  32
#define WS_M1    128
#define WS_QV    16512
#define WS_CB    16544
#define WS_LIST  16640
#define WS_GLIST 82176
#define WS_LOG   147712                 // float logits[2048][8]
#define WS_XF    (WS_LOG + 65536)       // fp16 x [2048][512]   (2 MB)
#define WS_W1F   (WS_XF + 2097152)      // fp16 W1^T [8][2048][512] (16 MB)
#define WS_W2F   (WS_W1F + 16777216)    // fp16 W2^T [8][512][2048] (16 MB)
#define WS_HF    (WS_W2F + 16777216)    // fp16 h [4096][2048] (16 MB)

__device__ __forceinline__ float wred(float v) {
#pragma unroll
  for (int o = 32; o > 0; o >>= 1) v += __shfl_down(v, o);
  return v;
}

__device__ __forceinline__ float wredx(float v) {
#pragma unroll
  for (int o = 32; o > 0; o >>= 1) v += __shfl_xor(v, o);
  return v;
}

__device__ __forceinline__ float block_sum(float v, float* s4, int tid) {
  v = wred(v);
  __syncthreads();
  if ((tid & 63) == 0) s4[tid >> 6] = v;
  __syncthreads();
  return s4[0] + s4[1] + s4[2] + s4[3];
}

__device__ __forceinline__ float gelu_f(float v) {
  return 0.5f * v * (1.0f + erff(v * 0.7071067811865475f));
}

#define GL16(gp, lp) __builtin_amdgcn_global_load_lds( \
    (const __attribute__((address_space(1))) void*)(gp), \
    (__attribute__((address_space(3))) void*)(lp), 16, 0, 0)

// ------------------------------------------------------------------
// Merged: precomp (blocks 0..512) + weight transpose/convert (rest).
// ------------------------------------------------------------------
__device__ __forceinline__ void convT_tile(const float* __restrict__ src,
    _Float16* __restrict__ dst, int R, int C, int bx, float* ls) {
  int nr = R >> 6, ncc = C >> 6;
  int e = bx / (nr * ncc);
  int rem = bx % (nr * ncc);
  int rt = rem / ncc, ct = rem % ncc;
  int tid = threadIdx.x;
  const float* s0 = src + (size_t)e * R * C + (size_t)(rt * 64) * C + ct * 64;
#pragma unroll
  for (int j = 0; j < 4; j++) {
    int li = j * 256 + tid;
    int rr = li >> 4, c4 = (li & 15) << 2;
    float4 v = *(const float4*)(s0 + (size_t)rr * C + c4);
    ls[rr * 65 + c4] = v.x;
    ls[rr * 65 + c4 + 1] = v.y;
    ls[rr * 65 + c4 + 2] = v.z;
    ls[rr * 65 + c4 + 3] = v.w;
  }
  __syncthreads();
#pragma unroll
  for (int j = 0; j < 4; j++) {
    int li = j * 256 + tid;
    int on = li >> 4, k4 = (li & 15) << 2;
    f16x4 o;
    o[0] = (_Float16)ls[(k4 + 0) * 65 + on];
    o[1] = (_Float16)ls[(k4 + 1) * 65 + on];
    o[2] = (_Float16)ls[(k4 + 2) * 65 + on];
    o[3] = (_Float16)ls[(k4 + 3) * 65 + on];
    *(f16x4*)(dst + ((size_t)e * C + ct * 64 + on) * R + rt * 64 + k4) = o;
  }
}

__global__ __launch_bounds__(256) void k_pre(
    const float* __restrict__ ctx_W, const float* __restrict__ rtr_W,
    const float* __restrict__ rtr_b, const float* __restrict__ qual_W,
    const float* __restrict__ qual_b, const float* __restrict__ ctx_b,
    const float* __restrict__ W1, const float* __restrict__ W2,
    float* __restrict__ M1, float* __restrict__ qv, float* __restrict__ cb,
    _Float16* __restrict__ w1f, _Float16* __restrict__ w2f) {
  __shared__ float ls[64 * 65];
  int bx = blockIdx.x;
  if (bx >= 513) {
    int cx = bx - 513;
    if (cx < Ee * 8 * 32) convT_tile(W1, w1f, Dd, Hh, cx, ls);
    else convT_tile(W2, w2f, Hh, Dd, cx - Ee * 8 * 32, ls);
    return;
  }
  int d = bx;
  int tid = threadIdx.x;
  if (tid >= 64) return;
  int lane = tid;
  if (d < Dd) {
    float acc[Ee] = {0.f, 0.f, 0.f, 0.f, 0.f, 0.f, 0.f, 0.f};
    for (int k = lane; k < Dd; k += 64) {
      float cw = ctx_W[d * Dd + k];
      const float* r = rtr_W + k * Ee;
#pragma unroll
      for (int e = 0; e < Ee; e++) acc[e] += cw * r[e];
    }
#pragma unroll
    for (int e = 0; e < Ee; e++) acc[e] = wred(acc[e]);
    if (lane == 0) {
#pragma unroll
      for (int e = 0; e < Ee; e++) M1[d * Ee + e] = acc[e];
    }
  } else {
    float aq[Ee] = {0.f, 0.f, 0.f, 0.f, 0.f, 0.f, 0.f, 0.f};
    float ab[Ee] = {0.f, 0.f, 0.f, 0.f, 0.f, 0.f, 0.f, 0.f};
    for (int k = lane; k < Dd; k += 64) {
      float qw = qual_W[k];
      float bb = ctx_b[k] + qual_b[k];
      const float* r = rtr_W + k * Ee;
#pragma unroll
      for (int e = 0; e < Ee; e++) {
        aq[e] += qw * r[e];
        ab[e] += bb * r[e];
      }
    }
#pragma unroll
    for (int e = 0; e < Ee; e++) {
      aq[e] = wred(aq[e]);
      ab[e] = wred(ab[e]);
    }
    if (lane == 0) {
#pragma unroll
      for (int e = 0; e < Ee; e++) {
        qv[e] = aq[e];
        cb[e] = ab[e] + rtr_b[e];
      }
    }
  }
}

// ------------------------------------------------------------------
// Logits + x->fp16: one wave per token.
// ------------------------------------------------------------------
__global__ __launch_bounds__(256) void k_logits(
    const float* __restrict__ x, const float* __restrict__ ctx,
    const float* __restrict__ quality, const float* __restrict__ rn_g,
    const float* __restrict__ rn_b, const float* __restrict__ cn_g,
    const float* __restrict__ cn_b, const float* __restrict__ rtr_W,
    const float* __restrict__ M1, const float* __restrict__ qv,
    const float* __restrict__ cb, const float* __restrict__ temperature,
    float* __restrict__ logitsS, _Float16* __restrict__ xf) {
  int wid = threadIdx.x >> 6, lane = threadIdx.x & 63;
  int t = blockIdx.x * 4 + wid;
  int d0 = lane * 8;

  float xv[8], cv[8];
  *(float4*)&xv[0] = *(const float4*)(x + (size_t)t * Dd + d0);
  *(float4*)&xv[4] = *(const float4*)(x + (size_t)t * Dd + d0 + 4);
  *(float4*)&cv[0] = *(const float4*)(ctx + (size_t)t * Dd + d0);
  *(float4*)&cv[4] = *(const float4*)(ctx + (size_t)t * Dd + d0 + 4);

  f16x8 xh;
#pragma unroll
  for (int d = 0; d < 8; d++) xh[d] = (_Float16)xv[d];
  *(f16x8*)(xf + (size_t)t * Dd + d0) = xh;

  float sx = 0.f, sc = 0.f;
#pragma unroll
  for (int d = 0; d < 8; d++) { sx += xv[d]; sc += cv[d]; }
  float mx = wredx(sx) * (1.f / Dd);
  float mc = wredx(sc) * (1.f / Dd);
  float vx = 0.f, vc = 0.f;
#pragma unroll
  for (int d = 0; d < 8; d++) {
    vx += (xv[d] - mx) * (xv[d] - mx);
    vc += (cv[d] - mc) * (cv[d] - mc);
  }
  float rsx = rsqrtf(wredx(vx) * (1.f / Dd) + 1e-5f);
  float rsc = rsqrtf(wredx(vc) * (1.f / Dd) + 1e-5f);

  float rg[8], rb[8], cg[8], cbb[8];
  *(float4*)&rg[0] = *(const float4*)(rn_g + d0);
  *(float4*)&rg[4] = *(const float4*)(rn_g + d0 + 4);
  *(float4*)&rb[0] = *(const float4*)(rn_b + d0);
  *(float4*)&rb[4] = *(const float4*)(rn_b + d0 + 4);
  *(float4*)&cg[0] = *(const float4*)(cn_g + d0);
  *(float4*)&cg[4] = *(const float4*)(cn_g + d0 + 4);
  *(float4*)&cbb[0] = *(const float4*)(cn_b + d0);
  *(float4*)&cbb[4] = *(const float4*)(cn_b + d0 + 4);

  float lg[Ee] = {0.f, 0.f, 0.f, 0.f, 0.f, 0.f, 0.f, 0.f};
#pragma unroll
  for (int d = 0; d < 8; d++) {
    float xn = (xv[d] - mx) * rsx * rg[d] + rb[d];
    float cn = (cv[d] - mc) * rsc * cg[d] + cbb[d];
    float rw[8], m1[8];
    *(float4*)&rw[0] = *(const float4*)(rtr_W + (size_t)(d0 + d) * Ee);
    *(float4*)&rw[4] = *(const float4*)(rtr_W + (size_t)(d0 + d) * Ee + 4);
    *(float4*)&m1[0] = *(const float4*)(M1 + (size_t)(d0 + d) * Ee);
    *(float4*)&m1[4] = *(const float4*)(M1 + (size_t)(d0 + d) * Ee + 4);
#pragma unroll
    for (int e = 0; e < Ee; e++) lg[e] += xn * rw[e] + cn * m1[e];
  }
#pragma unroll
  for (int e = 0; e < Ee; e++) lg[e] = wredx(lg[e]);

  if (lane == 0) {
    float invT = 1.f / fmaxf(temperature[0], 0.25f);
    float q = quality[t / Ss];
    float L[8];
#pragma unroll
    for (int e = 0; e < Ee; e++) L[e] = (lg[e] + q * qv[e] + cb[e]) * invT;
    *(float4*)(logitsS + (size_t)t * Ee) = *(float4*)&L[0];
    *(float4*)(logitsS + (size_t)t * Ee + 4) = *(float4*)&L[4];
  }
}

// ------------------------------------------------------------------
// Select: ONE block, top-2 + gates + stats + lists. No global atomics.
// ------------------------------------------------------------------
__global__ __launch_bounds__(256) void k_select(
    const float* __restrict__ logitsS, int* __restrict__ cnt,
    int* __restrict__ offs, int* __restrict__ list,
    float* __restrict__ glist, float* __restrict__ out) {
  __shared__ int scnt[Ee];
  __shared__ float s4[4];
  int tid = threadIdx.x;
  if (tid < Ee) scnt[tid] = 0;
  __syncthreads();

  float impL[Ee] = {0.f, 0.f, 0.f, 0.f, 0.f, 0.f, 0.f, 0.f};
  float zL = 0.f, eL = 0.f;

#pragma unroll
  for (int j = 0; j < 8; j++) {
    int t = j * 256 + tid;
    float L[8];
    *(float4*)&L[0] = *(const float4*)(logitsS + (size_t)t * Ee);
    *(float4*)&L[4] = *(const float4*)(logitsS + (size_t)t * Ee + 4);

    int i0 = 0;
#pragma unroll
    for (int e = 1; e < Ee; e++)
      if (L[e] > L[i0]) i0 = e;
    int i1 = (i0 == 0) ? 1 : 0;
#pragma unroll
    for (int e = 0; e < Ee; e++)
      if (e != i0 && L[e] > L[i1]) i1 = e;

    float e1 = __expf(L[i1] - L[i0]);
    float g0 = 1.f / (1.f + e1);
    float g1 = e1 / (1.f + e1);

    float m = L[i0];
    float p[8];
    float sum = 0.f;
#pragma unroll
    for (int e = 0; e < Ee; e++) {
      p[e] = __expf(L[e] - m);
      sum += p[e];
    }
    float lse = m + __logf(sum);
    float inv = 1.f / sum;
    zL += lse * lse;
#pragma unroll
    for (int e = 0; e < Ee; e++) {
      p[e] *= inv;
      eL -= p[e] * __logf(fmaxf(p[e], 1e-9f));
      impL[e] += p[e];
    }

    int s0 = atomicAdd(&scnt[i0], 1);
    list[i0 * CAP + s0] = t;
    glist[i0 * CAP + s0] = g0;
    int s1 = atomicAdd(&scnt[i1], 1);
    list[i1 * CAP + s1] = t;
    glist[i1 * CAP + s1] = g1;
  }

  float impS[Ee];
#pragma unroll
  for (int e = 0; e < Ee; e++) impS[e] = block_sum(impL[e], s4, tid);
  float zS = block_sum(zL, s4, tid);
  float eS = block_sum(eL, s4, tid);
  __syncthreads();

  if (tid == 0) {
    int s = 0;
#pragma unroll
    for (int e = 0; e < Ee; e++) {
      cnt[e] = scnt[e];
      offs[e] = s;
      s += scnt[e];
    }
    float lb = 0.f;
#pragma unroll
    for (int e = 0; e < Ee; e++) {
      float v = impS[e] * (1.f / TOKENS) - (1.f / Ee);
      lb += v * v;
    }
    lb *= (1.f / Ee);
    float rz = zS * (1.f / TOKENS);
    float en = eS * (1.f / TOKENS);
    float* sp = out + (size_t)Bb * Ss * Dd;
    sp[0] = lb;
    sp[1] = rz;
    sp[2] = en;
    sp[3] = lb + 0.001f * rz - 0.001f * en;
  }
}

// ------------------------------------------------------------------
// GEMM1 fp16: gathered X (ne x 512) @ W1[e] (512 x 2048), gelu -> hf
// 128x128 tile, BK=64, double-buffered prefetch (T3-min). grid: 8e x 16r x 16c
// ------------------------------------------------------------------
__global__ __launch_bounds__(256) void k_mg1(
    const _Float16* __restrict__ xf, const _Float16* __restrict__ w1f,
    const float* __restrict__ b1,
    const int* __restrict__ cnt, const int* __restrict__ offs,
    const int* __restrict__ list, _Float16* __restrict__ hf) {
  int bx = blockIdx.x;
  int e = bx >> 8;
  int r = (bx >> 4) & 15;
  int c = bx & 15;
  int ne = cnt[e];
  if (r * 128 >= ne) return;
  int off = offs[e];

  __shared__ _Float16 As[2][8 * 128 * 8];   // 16 KB x2
  __shared__ _Float16 Bs[2][8 * 128 * 8];   // 16 KB x2
  __shared__ int stok[128];

  int tid = threadIdx.x;
  if (tid < 128) {
    int row = r * 128 + tid;
    stok[tid] = list[e * CAP + ((row < ne) ? row : (ne - 1))];
  }
  __syncthreads();

  size_t asrc[4], bsrc[4];
  int lq[4];
#pragma unroll
  for (int q = 0; q < 4; q++) {
    int idx = q * 256 + tid;
    int g = idx >> 7, row = idx & 127;
    asrc[q] = (size_t)stok[row] * Dd + g * 8;
    bsrc[q] = ((size_t)(e * Hh + c * 128 + row)) * Dd + g * 8;
    lq[q] = idx * 8;
  }

  int lane = tid & 63, wid = tid >> 6;
  int wm = wid >> 1, wn = wid & 1;
  int l15 = lane & 15, lg = lane >> 4;

  f32x4 acc[4][4] = {};

  // prologue: stage k0=0 into buf 0
#pragma unroll
  for (int q = 0; q < 4; q++) {
    GL16(xf + asrc[q], &As[0][lq[q]]);
    GL16(w1f + bsrc[q], &Bs[0][lq[q]]);
  }
  __syncthreads();

  int cur = 0;
  for (int k0 = 0; k0 < Dd; k0 += 64) {
    if (k0 + 64 < Dd) {
#pragma unroll
      for (int q = 0; q < 4; q++) {
        GL16(xf + asrc[q] + k0 + 64, &As[cur ^ 1][lq[q]]);
        GL16(w1f + bsrc[q] + k0 + 64, &Bs[cur ^ 1][lq[q]]);
      }
    }
#pragma unroll
    for (int ks = 0; ks < 2; ks++) {
      f16x8 a[4], b[4];
#pragma unroll
      for (int m = 0; m < 4; m++)
        a[m] = *(const f16x8*)&As[cur][(((ks * 4 + lg) << 7) + wm * 64 + m * 16 + l15) * 8];
#pragma unroll
      for (int n = 0; n < 4; n++)
        b[n] = *(const f16x8*)&Bs[cur][(((ks * 4 + lg) << 7) + wn * 64 + n * 16 + l15) * 8];
#pragma unroll
      for (int m = 0; m < 4; m++)
#pragma unroll
        for (int n = 0; n < 4; n++)
          acc[m][n] = __builtin_amdgcn_mfma_f32_16x16x32_f16(a[m], b[n], acc[m][n], 0, 0, 0);
    }
    __syncthreads();   // drains vmcnt for next-tile stage + lgkm; protects buffer reuse
    cur ^= 1;
  }

  int lg4 = lg * 4;
#pragma unroll
  for (int n = 0; n < 4; n++) {
    int colg = c * 128 + wn * 64 + n * 16 + l15;
    float bias = b1[e * Hh + colg];
#pragma unroll
    for (int m = 0; m < 4; m++) {
#pragma unroll
      for (int j = 0; j < 4; j++) {
        int rowl = r * 128 + wm * 64 + m * 16 + lg4 + j;
        if (rowl < ne)
          hf[(size_t)(off + rowl) * Hh + colg] = (_Float16)gelu_f(acc[m][n][j] + bias);
      }
    }
  }
}

// ------------------------------------------------------------------
// GEMM2 fp16: hf (ne x 2048) @ W2[e] (2048 x 512), +b2, gate, atomic scatter
// 128x128 tile, BK=64, split-K=4, double-buffered prefetch. grid: 8e x 16r x 4c x 4k
// ------------------------------------------------------------------
__global__ __launch_bounds__(256) void k_mg2(
    const _Float16* __restrict__ hf, const _Float16* __restrict__ w2f,
    const float* __restrict__ b2,
    const int* __restrict__ cnt, const int* __restrict__ offs,
    const int* __restrict__ list, const float* __restrict__ glist,
    float* __restrict__ out) {
  int bx = blockIdx.x;
  int e = bx >> 8;
  int r = (bx >> 4) & 15;
  int c = (bx >> 2) & 3;
  int kS = bx & 3;
  int ne = cnt[e];
  if (r * 128 >= ne) return;
  int off = offs[e];

  __shared__ _Float16 As[2][8 * 128 * 8];
  __shared__ _Float16 Bs[2][8 * 128 * 8];

  int tid = threadIdx.x;
  size_t kbase = (size_t)kS * 512;

  size_t asrc[4], bsrc[4];
  int lq[4];
#pragma unroll
  for (int q = 0; q < 4; q++) {
    int idx = q * 256 + tid;
    int g = idx >> 7, row = idx & 127;
    int ar = r * 128 + row;
    if (ar >= ne) ar = ne - 1;
    asrc[q] = (size_t)(off + ar) * Hh + kbase + g * 8;
    bsrc[q] = ((size_t)(e * Dd + c * 128 + row)) * Hh + kbase + g * 8;
    lq[q] = idx * 8;
  }

  int lane = tid & 63, wid = tid >> 6;
  int wm = wid >> 1, wn = wid & 1;
  int l15 = lane & 15, lg = lane >> 4;

  f32x4 acc[4][4] = {};

  // prologue: stage k0=0 into buf 0
#pragma unroll
  for (int q = 0; q < 4; q++) {
    GL16(hf + asrc[q], &As[0][lq[q]]);
    GL16(w2f + bsrc[q], &Bs[0][lq[q]]);
  }
  __syncthreads();

  int cur = 0;
  for (int k0 = 0; k0 < 512; k0 += 64) {
    if (k0 + 64 < 512) {
#pragma unroll
      for (int q = 0; q < 4; q++) {
        GL16(hf + asrc[q] + k0 + 64, &As[cur ^ 1][lq[q]]);
        GL16(w2f + bsrc[q] + k0 + 64, &Bs[cur ^ 1][lq[q]]);
      }
    }
#pragma unroll
    for (int ks = 0; ks < 2; ks++) {
      f16x8 a[4], b[4];
#pragma unroll
      for (int m = 0; m < 4; m++)
        a[m] = *(const f16x8*)&As[cur][(((ks * 4 + lg) << 7) + wm * 64 + m * 16 + l15) * 8];
#pragma unroll
      for (int n = 0; n < 4; n++)
        b[n] = *(const f16x8*)&Bs[cur][(((ks * 4 + lg) << 7) + wn * 64 + n * 16 + l15) * 8];
#pragma unroll
      for (int m = 0; m < 4; m++)
#pragma unroll
        for (int n = 0; n < 4; n++)
          acc[m][n] = __builtin_amdgcn_mfma_f32_16x16x32_f16(a[m], b[n], acc[m][n], 0, 0, 0);
    }
    __syncthreads();
    cur ^= 1;
  }

  int lg4 = lg * 4;
#pragma unroll
  for (int m = 0; m < 4; m++) {
#pragma unroll
    for (int j = 0; j < 4; j++) {
      int rowl = r * 128 + wm * 64 + m * 16 + lg4 + j;
      if (rowl < ne) {
        int tok = list[e * CAP + rowl];
        float gte = glist[e * CAP + rowl];
#pragma unroll
        for (int n = 0; n < 4; n++) {
          int colg = c * 128 + wn * 64 + n * 16 + l15;
          float v = acc[m][n][j] + (kS == 0 ? b2[e * Dd + colg] : 0.f);
          atomicAdd(&out[(size_t)tok * Dd + colg], gte * v);
        }
      }
    }
  }
}

extern "C" void kernel_launch(void* const* d_in, const int* in_sizes, int n_in,
                              void* d_out, int out_size, void* d_ws, size_t ws_size,
                              hipStream_t stream) {
  const float* x = (const float*)d_in[0];
  const float* ctx = (const float*)d_in[1];
  const float* quality = (const float*)d_in[2];
  const float* rn_g = (const float*)d_in[3];
  const float* rn_b = (const float*)d_in[4];
  const float* cn_g = (const float*)d_in[5];
  const float* cn_b = (const float*)d_in[6];
  const float* ctx_W = (const float*)d_in[7];
  const float* ctx_b = (const float*)d_in[8];
  const float* qual_W = (const float*)d_in[9];
  const float* qual_b = (const float*)d_in[10];
  const float* rtr_W = (const float*)d_in[11];
  const float* rtr_b = (const float*)d_in[12];
  const float* temperature = (const float*)d_in[13];
  const float* W1 = (const float*)d_in[14];
  const float* b1 = (const float*)d_in[15];
  const float* W2 = (const float*)d_in[16];
  const float* b2 = (const float*)d_in[17];
  float* out = (float*)d_out;

  char* w = (char*)d_ws;
  int* cnt = (int*)(w + WS_CNT);
  int* offs = (int*)(w + WS_OFFS);
  float* M1 = (float*)(w + WS_M1);
  float* qv = (float*)(w + WS_QV);
  float* cb = (float*)(w + WS_CB);
  int* list = (int*)(w + WS_LIST);
  float* glist = (float*)(w + WS_GLIST);
  float* logitsS = (float*)(w + WS_LOG);
  _Float16* xf = (_Float16*)(w + WS_XF);
  _Float16* w1f = (_Float16*)(w + WS_W1F);
  _Float16* w2f = (_Float16*)(w + WS_W2F);
  _Float16* hf = (_Float16*)(w + WS_HF);

  hipMemsetAsync(d_out, 0, (size_t)out_size * sizeof(float), stream);

  k_pre<<<513 + Ee * 8 * 32 * 2, 256, 0, stream>>>(
      ctx_W, rtr_W, rtr_b, qual_W, qual_b, ctx_b, W1, W2, M1, qv, cb, w1f, w2f);
  k_logits<<<TOKENS / 4, 256, 0, stream>>>(x, ctx, quality, rn_g, rn_b, cn_g, cn_b, rtr_W,
                                           M1, qv, cb, temperature, logitsS, xf);
  k_select<<<1, 256, 0, stream>>>(logitsS, cnt, offs, list, glist, out);
  k_mg1<<<Ee * 16 * 16, 256, 0, stream>>>(xf, w1f, b1, cnt, offs, list, hf);
  k_mg2<<<Ee * 16 * 4 * 4, 256, 0, stream>>>(hf, w2f, b2, cnt, offs, list, glist, out);
}

// Round 8
// 256.653 us; speedup vs baseline: 1.1706x; 1.1706x over previous
//
#include <hip/hip_runtime.h>
#include <hip/hip_bf16.h>
#include <math.h>

#define Bb 4
#define Ss 512
#define Dd 512
#define Hh 2048
#define Ee 8
#define TOKENS 2048
#define CAP 2048

typedef __attribute__((ext_vector_type(8))) _Float16 f16x8;
typedef __attribute__((ext_vector_type(4))) _Float16 f16x4;
typedef __attribute__((ext_vector_type(4))) float f32x4;

// ---------------- ws layout (bytes) ----------------
#define WS_CNT   0
#define WS_OFFS  32
#define WS_M1    128
#define WS_QV    16512
#define WS_CB    16544
#define WS_LIST  16640
#define WS_GLIST 82176
#define WS_LOG   147712                 // float logits[2048][8]
#define WS_XF    (WS_LOG + 65536)       // fp16 x [2048][512]   (2 MB)
#define WS_W1F   (WS_XF + 2097152)      // fp16 W1^T [8][2048][512] (16 MB)
#define WS_W2F   (WS_W1F + 16777216)    // fp16 W2^T [8][512][2048] (16 MB)
#define WS_HF    (WS_W2F + 16777216)    // fp16 h [4096][2048] (16 MB)
#define WS_YB    (WS_HF + 16777216)     // fp16 ybuf [4][4096][512] (16 MB)
#define WS_SEL   (WS_YB + 16777216)     // int sel [2048*2] (16 KB)
// end ~66 MB (ws >= 100 MB proven in round 1/2)

__device__ __forceinline__ float wred(float v) {
#pragma unroll
  for (int o = 32; o > 0; o >>= 1) v += __shfl_down(v, o);
  return v;
}

__device__ __forceinline__ float wredx(float v) {
#pragma unroll
  for (int o = 32; o > 0; o >>= 1) v += __shfl_xor(v, o);
  return v;
}

__device__ __forceinline__ float block_sum(float v, float* s4, int tid) {
  v = wred(v);
  __syncthreads();
  if ((tid & 63) == 0) s4[tid >> 6] = v;
  __syncthreads();
  return s4[0] + s4[1] + s4[2] + s4[3];
}

__device__ __forceinline__ float gelu_f(float v) {
  return 0.5f * v * (1.0f + erff(v * 0.7071067811865475f));
}

#define GL16(gp, lp) __builtin_amdgcn_global_load_lds( \
    (const __attribute__((address_space(1))) void*)(gp), \
    (__attribute__((address_space(3))) void*)(lp), 16, 0, 0)

// ------------------------------------------------------------------
// Merged: precomp (blocks 0..512) + weight transpose/convert (rest).
// ------------------------------------------------------------------
__device__ __forceinline__ void convT_tile(const float* __restrict__ src,
    _Float16* __restrict__ dst, int R, int C, int bx, float* ls) {
  int nr = R >> 6, ncc = C >> 6;
  int e = bx / (nr * ncc);
  int rem = bx % (nr * ncc);
  int rt = rem / ncc, ct = rem % ncc;
  int tid = threadIdx.x;
  const float* s0 = src + (size_t)e * R * C + (size_t)(rt * 64) * C + ct * 64;
#pragma unroll
  for (int j = 0; j < 4; j++) {
    int li = j * 256 + tid;
    int rr = li >> 4, c4 = (li & 15) << 2;
    float4 v = *(const float4*)(s0 + (size_t)rr * C + c4);
    ls[rr * 65 + c4] = v.x;
    ls[rr * 65 + c4 + 1] = v.y;
    ls[rr * 65 + c4 + 2] = v.z;
    ls[rr * 65 + c4 + 3] = v.w;
  }
  __syncthreads();
#pragma unroll
  for (int j = 0; j < 4; j++) {
    int li = j * 256 + tid;
    int on = li >> 4, k4 = (li & 15) << 2;
    f16x4 o;
    o[0] = (_Float16)ls[(k4 + 0) * 65 + on];
    o[1] = (_Float16)ls[(k4 + 1) * 65 + on];
    o[2] = (_Float16)ls[(k4 + 2) * 65 + on];
    o[3] = (_Float16)ls[(k4 + 3) * 65 + on];
    *(f16x4*)(dst + ((size_t)e * C + ct * 64 + on) * R + rt * 64 + k4) = o;
  }
}

__global__ __launch_bounds__(256) void k_pre(
    const float* __restrict__ ctx_W, const float* __restrict__ rtr_W,
    const float* __restrict__ rtr_b, const float* __restrict__ qual_W,
    const float* __restrict__ qual_b, const float* __restrict__ ctx_b,
    const float* __restrict__ W1, const float* __restrict__ W2,
    float* __restrict__ M1, float* __restrict__ qv, float* __restrict__ cb,
    _Float16* __restrict__ w1f, _Float16* __restrict__ w2f) {
  __shared__ float ls[64 * 65];
  int bx = blockIdx.x;
  if (bx >= 513) {
    int cx = bx - 513;
    if (cx < Ee * 8 * 32) convT_tile(W1, w1f, Dd, Hh, cx, ls);
    else convT_tile(W2, w2f, Hh, Dd, cx - Ee * 8 * 32, ls);
    return;
  }
  int d = bx;
  int tid = threadIdx.x;
  if (tid >= 64) return;
  int lane = tid;
  if (d < Dd) {
    float acc[Ee] = {0.f, 0.f, 0.f, 0.f, 0.f, 0.f, 0.f, 0.f};
    for (int k = lane; k < Dd; k += 64) {
      float cw = ctx_W[d * Dd + k];
      const float* r = rtr_W + k * Ee;
#pragma unroll
      for (int e = 0; e < Ee; e++) acc[e] += cw * r[e];
    }
#pragma unroll
    for (int e = 0; e < Ee; e++) acc[e] = wred(acc[e]);
    if (lane == 0) {
#pragma unroll
      for (int e = 0; e < Ee; e++) M1[d * Ee + e] = acc[e];
    }
  } else {
    float aq[Ee] = {0.f, 0.f, 0.f, 0.f, 0.f, 0.f, 0.f, 0.f};
    float ab[Ee] = {0.f, 0.f, 0.f, 0.f, 0.f, 0.f, 0.f, 0.f};
    for (int k = lane; k < Dd; k += 64) {
      float qw = qual_W[k];
      float bb = ctx_b[k] + qual_b[k];
      const float* r = rtr_W + k * Ee;
#pragma unroll
      for (int e = 0; e < Ee; e++) {
        aq[e] += qw * r[e];
        ab[e] += bb * r[e];
      }
    }
#pragma unroll
    for (int e = 0; e < Ee; e++) {
      aq[e] = wred(aq[e]);
      ab[e] = wred(ab[e]);
    }
    if (lane == 0) {
#pragma unroll
      for (int e = 0; e < Ee; e++) {
        qv[e] = aq[e];
        cb[e] = ab[e] + rtr_b[e];
      }
    }
  }
}

// ------------------------------------------------------------------
// Logits + x->fp16: one wave per token.
// ------------------------------------------------------------------
__global__ __launch_bounds__(256) void k_logits(
    const float* __restrict__ x, const float* __restrict__ ctx,
    const float* __restrict__ quality, const float* __restrict__ rn_g,
    const float* __restrict__ rn_b, const float* __restrict__ cn_g,
    const float* __restrict__ cn_b, const float* __restrict__ rtr_W,
    const float* __restrict__ M1, const float* __restrict__ qv,
    const float* __restrict__ cb, const float* __restrict__ temperature,
    float* __restrict__ logitsS, _Float16* __restrict__ xf) {
  int wid = threadIdx.x >> 6, lane = threadIdx.x & 63;
  int t = blockIdx.x * 4 + wid;
  int d0 = lane * 8;

  float xv[8], cv[8];
  *(float4*)&xv[0] = *(const float4*)(x + (size_t)t * Dd + d0);
  *(float4*)&xv[4] = *(const float4*)(x + (size_t)t * Dd + d0 + 4);
  *(float4*)&cv[0] = *(const float4*)(ctx + (size_t)t * Dd + d0);
  *(float4*)&cv[4] = *(const float4*)(ctx + (size_t)t * Dd + d0 + 4);

  f16x8 xh;
#pragma unroll
  for (int d = 0; d < 8; d++) xh[d] = (_Float16)xv[d];
  *(f16x8*)(xf + (size_t)t * Dd + d0) = xh;

  float sx = 0.f, sc = 0.f;
#pragma unroll
  for (int d = 0; d < 8; d++) { sx += xv[d]; sc += cv[d]; }
  float mx = wredx(sx) * (1.f / Dd);
  float mc = wredx(sc) * (1.f / Dd);
  float vx = 0.f, vc = 0.f;
#pragma unroll
  for (int d = 0; d < 8; d++) {
    vx += (xv[d] - mx) * (xv[d] - mx);
    vc += (cv[d] - mc) * (cv[d] - mc);
  }
  float rsx = rsqrtf(wredx(vx) * (1.f / Dd) + 1e-5f);
  float rsc = rsqrtf(wredx(vc) * (1.f / Dd) + 1e-5f);

  float rg[8], rb[8], cg[8], cbb[8];
  *(float4*)&rg[0] = *(const float4*)(rn_g + d0);
  *(float4*)&rg[4] = *(const float4*)(rn_g + d0 + 4);
  *(float4*)&rb[0] = *(const float4*)(rn_b + d0);
  *(float4*)&rb[4] = *(const float4*)(rn_b + d0 + 4);
  *(float4*)&cg[0] = *(const float4*)(cn_g + d0);
  *(float4*)&cg[4] = *(const float4*)(cn_g + d0 + 4);
  *(float4*)&cbb[0] = *(const float4*)(cn_b + d0);
  *(float4*)&cbb[4] = *(const float4*)(cn_b + d0 + 4);

  float lg[Ee] = {0.f, 0.f, 0.f, 0.f, 0.f, 0.f, 0.f, 0.f};
#pragma unroll
  for (int d = 0; d < 8; d++) {
    float xn = (xv[d] - mx) * rsx * rg[d] + rb[d];
    float cn = (cv[d] - mc) * rsc * cg[d] + cbb[d];
    float rw[8], m1[8];
    *(float4*)&rw[0] = *(const float4*)(rtr_W + (size_t)(d0 + d) * Ee);
    *(float4*)&rw[4] = *(const float4*)(rtr_W + (size_t)(d0 + d) * Ee + 4);
    *(float4*)&m1[0] = *(const float4*)(M1 + (size_t)(d0 + d) * Ee);
    *(float4*)&m1[4] = *(const float4*)(M1 + (size_t)(d0 + d) * Ee + 4);
#pragma unroll
    for (int e = 0; e < Ee; e++) lg[e] += xn * rw[e] + cn * m1[e];
  }
#pragma unroll
  for (int e = 0; e < Ee; e++) lg[e] = wredx(lg[e]);

  if (lane == 0) {
    float invT = 1.f / fmaxf(temperature[0], 0.25f);
    float q = quality[t / Ss];
    float L[8];
#pragma unroll
    for (int e = 0; e < Ee; e++) L[e] = (lg[e] + q * qv[e] + cb[e]) * invT;
    *(float4*)(logitsS + (size_t)t * Ee) = *(float4*)&L[0];
    *(float4*)(logitsS + (size_t)t * Ee + 4) = *(float4*)&L[4];
  }
}

// ------------------------------------------------------------------
// Select: ONE block, top-2 + gates + stats + lists + inverse map.
// ------------------------------------------------------------------
__global__ __launch_bounds__(256) void k_select(
    const float* __restrict__ logitsS, int* __restrict__ cnt,
    int* __restrict__ offs, int* __restrict__ list,
    float* __restrict__ glist, int* __restrict__ sel,
    float* __restrict__ out) {
  __shared__ int scnt[Ee];
  __shared__ float s4[4];
  int tid = threadIdx.x;
  if (tid < Ee) scnt[tid] = 0;
  __syncthreads();

  float impL[Ee] = {0.f, 0.f, 0.f, 0.f, 0.f, 0.f, 0.f, 0.f};
  float zL = 0.f, eL = 0.f;

#pragma unroll
  for (int j = 0; j < 8; j++) {
    int t = j * 256 + tid;
    float L[8];
    *(float4*)&L[0] = *(const float4*)(logitsS + (size_t)t * Ee);
    *(float4*)&L[4] = *(const float4*)(logitsS + (size_t)t * Ee + 4);

    int i0 = 0;
#pragma unroll
    for (int e = 1; e < Ee; e++)
      if (L[e] > L[i0]) i0 = e;
    int i1 = (i0 == 0) ? 1 : 0;
#pragma unroll
    for (int e = 0; e < Ee; e++)
      if (e != i0 && L[e] > L[i1]) i1 = e;

    float e1 = __expf(L[i1] - L[i0]);
    float g0 = 1.f / (1.f + e1);
    float g1 = e1 / (1.f + e1);

    float m = L[i0];
    float p[8];
    float sum = 0.f;
#pragma unroll
    for (int e = 0; e < Ee; e++) {
      p[e] = __expf(L[e] - m);
      sum += p[e];
    }
    float lse = m + __logf(sum);
    float inv = 1.f / sum;
    zL += lse * lse;
#pragma unroll
    for (int e = 0; e < Ee; e++) {
      p[e] *= inv;
      eL -= p[e] * __logf(fmaxf(p[e], 1e-9f));
      impL[e] += p[e];
    }

    int s0 = atomicAdd(&scnt[i0], 1);
    list[i0 * CAP + s0] = t;
    glist[i0 * CAP + s0] = g0;
    sel[t * 2 + 0] = (i0 << 12) | s0;
    int s1 = atomicAdd(&scnt[i1], 1);
    list[i1 * CAP + s1] = t;
    glist[i1 * CAP + s1] = g1;
    sel[t * 2 + 1] = (i1 << 12) | s1;
  }

  float impS[Ee];
#pragma unroll
  for (int e = 0; e < Ee; e++) impS[e] = block_sum(impL[e], s4, tid);
  float zS = block_sum(zL, s4, tid);
  float eS = block_sum(eL, s4, tid);
  __syncthreads();

  if (tid == 0) {
    int s = 0;
#pragma unroll
    for (int e = 0; e < Ee; e++) {
      cnt[e] = scnt[e];
      offs[e] = s;
      s += scnt[e];
    }
    float lb = 0.f;
#pragma unroll
    for (int e = 0; e < Ee; e++) {
      float v = impS[e] * (1.f / TOKENS) - (1.f / Ee);
      lb += v * v;
    }
    lb *= (1.f / Ee);
    float rz = zS * (1.f / TOKENS);
    float en = eS * (1.f / TOKENS);
    float* sp = out + (size_t)Bb * Ss * Dd;
    sp[0] = lb;
    sp[1] = rz;
    sp[2] = en;
    sp[3] = lb + 0.001f * rz - 0.001f * en;
  }
}

// ------------------------------------------------------------------
// GEMM1 fp16: gathered X (ne x 512) @ W1[e] (512 x 2048), gelu -> hf
// 128x128 tile, BK=64, single buffer (R6 structure). grid: 8e x 16r x 16c
// ------------------------------------------------------------------
__global__ __launch_bounds__(256) void k_mg1(
    const _Float16* __restrict__ xf, const _Float16* __restrict__ w1f,
    const float* __restrict__ b1,
    const int* __restrict__ cnt, const int* __restrict__ offs,
    const int* __restrict__ list, _Float16* __restrict__ hf) {
  int bx = blockIdx.x;
  int e = bx >> 8;
  int r = (bx >> 4) & 15;
  int c = bx & 15;
  int ne = cnt[e];
  if (r * 128 >= ne) return;
  int off = offs[e];

  __shared__ _Float16 As[8 * 128 * 8];   // 16 KB  [g:8][row:128][8]
  __shared__ _Float16 Bs[8 * 128 * 8];   // 16 KB
  __shared__ int stok[128];

  int tid = threadIdx.x;
  if (tid < 128) {
    int row = r * 128 + tid;
    stok[tid] = list[e * CAP + ((row < ne) ? row : (ne - 1))];
  }
  __syncthreads();

  size_t asrc[4], bsrc[4];
  int lq[4];
#pragma unroll
  for (int q = 0; q < 4; q++) {
    int idx = q * 256 + tid;
    int g = idx >> 7, row = idx & 127;
    asrc[q] = (size_t)stok[row] * Dd + g * 8;
    bsrc[q] = ((size_t)(e * Hh + c * 128 + row)) * Dd + g * 8;
    lq[q] = idx * 8;
  }

  int lane = tid & 63, wid = tid >> 6;
  int wm = wid >> 1, wn = wid & 1;
  int l15 = lane & 15, lg = lane >> 4;

  f32x4 acc[4][4] = {};

  for (int k0 = 0; k0 < Dd; k0 += 64) {
#pragma unroll
    for (int q = 0; q < 4; q++) {
      GL16(xf + asrc[q] + k0, &As[lq[q]]);
      GL16(w1f + bsrc[q] + k0, &Bs[lq[q]]);
    }
    __syncthreads();
    f16x8 a[2][4], b[2][4];
#pragma unroll
    for (int ks = 0; ks < 2; ks++) {
#pragma unroll
      for (int m = 0; m < 4; m++)
        a[ks][m] = *(const f16x8*)&As[(((ks * 4 + lg) << 7) + wm * 64 + m * 16 + l15) * 8];
#pragma unroll
      for (int n = 0; n < 4; n++)
        b[ks][n] = *(const f16x8*)&Bs[(((ks * 4 + lg) << 7) + wn * 64 + n * 16 + l15) * 8];
    }
#pragma unroll
    for (int ks = 0; ks < 2; ks++)
#pragma unroll
      for (int m = 0; m < 4; m++)
#pragma unroll
        for (int n = 0; n < 4; n++)
          acc[m][n] = __builtin_amdgcn_mfma_f32_16x16x32_f16(a[ks][m], b[ks][n], acc[m][n], 0, 0, 0);
    __syncthreads();
  }

  int lg4 = lg * 4;
#pragma unroll
  for (int n = 0; n < 4; n++) {
    int colg = c * 128 + wn * 64 + n * 16 + l15;
    float bias = b1[e * Hh + colg];
#pragma unroll
    for (int m = 0; m < 4; m++) {
#pragma unroll
      for (int j = 0; j < 4; j++) {
        int rowl = r * 128 + wm * 64 + m * 16 + lg4 + j;
        if (rowl < ne)
          hf[(size_t)(off + rowl) * Hh + colg] = (_Float16)gelu_f(acc[m][n][j] + bias);
      }
    }
  }
}

// ------------------------------------------------------------------
// GEMM2 fp16: hf (ne x 2048) @ W2[e] (2048 x 512), split-K=4,
// NON-ATOMIC fp16 partials -> ybuf[kS][slot][512]. grid: 8e x 16r x 4c x 4k
// ------------------------------------------------------------------
__global__ __launch_bounds__(256) void k_mg2(
    const _Float16* __restrict__ hf, const _Float16* __restrict__ w2f,
    const int* __restrict__ cnt, const int* __restrict__ offs,
    _Float16* __restrict__ yb) {
  int bx = blockIdx.x;
  int e = bx >> 8;
  int r = (bx >> 4) & 15;
  int c = (bx >> 2) & 3;
  int kS = bx & 3;
  int ne = cnt[e];
  if (r * 128 >= ne) return;
  int off = offs[e];

  __shared__ _Float16 As[8 * 128 * 8];
  __shared__ _Float16 Bs[8 * 128 * 8];

  int tid = threadIdx.x;
  size_t kbase = (size_t)kS * 512;

  size_t asrc[4], bsrc[4];
  int lq[4];
#pragma unroll
  for (int q = 0; q < 4; q++) {
    int idx = q * 256 + tid;
    int g = idx >> 7, row = idx & 127;
    int ar = r * 128 + row;
    if (ar >= ne) ar = ne - 1;
    asrc[q] = (size_t)(off + ar) * Hh + kbase + g * 8;
    bsrc[q] = ((size_t)(e * Dd + c * 128 + row)) * Hh + kbase + g * 8;
    lq[q] = idx * 8;
  }

  int lane = tid & 63, wid = tid >> 6;
  int wm = wid >> 1, wn = wid & 1;
  int l15 = lane & 15, lg = lane >> 4;

  f32x4 acc[4][4] = {};

  for (int k0 = 0; k0 < 512; k0 += 64) {
#pragma unroll
    for (int q = 0; q < 4; q++) {
      GL16(hf + asrc[q] + k0, &As[lq[q]]);
      GL16(w2f + bsrc[q] + k0, &Bs[lq[q]]);
    }
    __syncthreads();
    f16x8 a[2][4], b[2][4];
#pragma unroll
    for (int ks = 0; ks < 2; ks++) {
#pragma unroll
      for (int m = 0; m < 4; m++)
        a[ks][m] = *(const f16x8*)&As[(((ks * 4 + lg) << 7) + wm * 64 + m * 16 + l15) * 8];
#pragma unroll
      for (int n = 0; n < 4; n++)
        b[ks][n] = *(const f16x8*)&Bs[(((ks * 4 + lg) << 7) + wn * 64 + n * 16 + l15) * 8];
    }
#pragma unroll
    for (int ks = 0; ks < 2; ks++)
#pragma unroll
      for (int m = 0; m < 4; m++)
#pragma unroll
        for (int n = 0; n < 4; n++)
          acc[m][n] = __builtin_amdgcn_mfma_f32_16x16x32_f16(a[ks][m], b[ks][n], acc[m][n], 0, 0, 0);
    __syncthreads();
  }

  int lg4 = lg * 4;
#pragma unroll
  for (int m = 0; m < 4; m++) {
#pragma unroll
    for (int j = 0; j < 4; j++) {
      int rowl = r * 128 + wm * 64 + m * 16 + lg4 + j;
      if (rowl < ne) {
        _Float16* yp = yb + ((size_t)kS * 4096 + off + rowl) * Dd;
#pragma unroll
        for (int n = 0; n < 4; n++) {
          int colg = c * 128 + wn * 64 + n * 16 + l15;
          yp[colg] = (_Float16)acc[m][n][j];
        }
      }
    }
  }
}

// ------------------------------------------------------------------
// Combine: out[t] = sum_k gate_k * (sum_s yb[s][slot_k] + b2[e_k]).
// 4 tokens/block (wave each), 8 cols/thread. grid: TOKENS/4
// ------------------------------------------------------------------
__global__ __launch_bounds__(256) void k_comb(
    const _Float16* __restrict__ yb, const int* __restrict__ sel,
    const float* __restrict__ glist, const int* __restrict__ offs,
    const float* __restrict__ b2, float* __restrict__ out) {
  int t = blockIdx.x * 4 + (threadIdx.x >> 6);
  int lane = threadIdx.x & 63;
  int c0 = lane * 8;

  float acc[8] = {0.f, 0.f, 0.f, 0.f, 0.f, 0.f, 0.f, 0.f};
#pragma unroll
  for (int k = 0; k < 2; k++) {
    int pk = sel[t * 2 + k];
    int e = pk >> 12, pos = pk & 4095;
    int slot = offs[e] + pos;
    float g = glist[e * CAP + pos];
    float pa[8] = {0.f, 0.f, 0.f, 0.f, 0.f, 0.f, 0.f, 0.f};
#pragma unroll
    for (int s = 0; s < 4; s++) {
      f16x8 v = *(const f16x8*)(yb + ((size_t)s * 4096 + slot) * Dd + c0);
#pragma unroll
      for (int j = 0; j < 8; j++) pa[j] += (float)v[j];
    }
    const float* bb = b2 + e * Dd + c0;
    float b4[8];
    *(float4*)&b4[0] = *(const float4*)bb;
    *(float4*)&b4[4] = *(const float4*)(bb + 4);
#pragma unroll
    for (int j = 0; j < 8; j++) acc[j] += g * (pa[j] + b4[j]);
  }
  float* op = out + (size_t)t * Dd + c0;
  *(float4*)op = *(float4*)&acc[0];
  *(float4*)(op + 4) = *(float4*)&acc[4];
}

extern "C" void kernel_launch(void* const* d_in, const int* in_sizes, int n_in,
                              void* d_out, int out_size, void* d_ws, size_t ws_size,
                              hipStream_t stream) {
  const float* x = (const float*)d_in[0];
  const float* ctx = (const float*)d_in[1];
  const float* quality = (const float*)d_in[2];
  const float* rn_g = (const float*)d_in[3];
  const float* rn_b = (const float*)d_in[4];
  const float* cn_g = (const float*)d_in[5];
  const float* cn_b = (const float*)d_in[6];
  const float* ctx_W = (const float*)d_in[7];
  const float* ctx_b = (const float*)d_in[8];
  const float* qual_W = (const float*)d_in[9];
  const float* qual_b = (const float*)d_in[10];
  const float* rtr_W = (const float*)d_in[11];
  const float* rtr_b = (const float*)d_in[12];
  const float* temperature = (const float*)d_in[13];
  const float* W1 = (const float*)d_in[14];
  const float* b1 = (const float*)d_in[15];
  const float* W2 = (const float*)d_in[16];
  const float* b2 = (const float*)d_in[17];
  float* out = (float*)d_out;

  char* w = (char*)d_ws;
  int* cnt = (int*)(w + WS_CNT);
  int* offs = (int*)(w + WS_OFFS);
  float* M1 = (float*)(w + WS_M1);
  float* qv = (float*)(w + WS_QV);
  float* cb = (float*)(w + WS_CB);
  int* list = (int*)(w + WS_LIST);
  float* glist = (float*)(w + WS_GLIST);
  float* logitsS = (float*)(w + WS_LOG);
  _Float16* xf = (_Float16*)(w + WS_XF);
  _Float16* w1f = (_Float16*)(w + WS_W1F);
  _Float16* w2f = (_Float16*)(w + WS_W2F);
  _Float16* hf = (_Float16*)(w + WS_HF);
  _Float16* yb = (_Float16*)(w + WS_YB);
  int* sel = (int*)(w + WS_SEL);

  k_pre<<<513 + Ee * 8 * 32 * 2, 256, 0, stream>>>(
      ctx_W, rtr_W, rtr_b, qual_W, qual_b, ctx_b, W1, W2, M1, qv, cb, w1f, w2f);
  k_logits<<<TOKENS / 4, 256, 0, stream>>>(x, ctx, quality, rn_g, rn_b, cn_g, cn_b, rtr_W,
                                           M1, qv, cb, temperature, logitsS, xf);
  k_select<<<1, 256, 0, stream>>>(logitsS, cnt, offs, list, glist, sel, out);
  k_mg1<<<Ee * 16 * 16, 256, 0, stream>>>(xf, w1f, b1, cnt, offs, list, hf);
  k_mg2<<<Ee * 16 * 4 * 4, 256, 0, stream>>>(hf, w2f, cnt, offs, yb);
  k_comb<<<TOKENS / 4, 256, 0, stream>>>(yb, sel, glist, offs, b2, out);
}

// Round 9
// 238.548 us; speedup vs baseline: 1.2595x; 1.0759x over previous
//
#include <hip/hip_runtime.h>
#include <hip/hip_bf16.h>
#include <math.h>

#define Bb 4
#define Ss 512
#define Dd 512
#define Hh 2048
#define Ee 8
#define TOKENS 2048
#define CAP 2048
#define SLOTS 5120   // padded slot capacity (4096 + 8*127 rounded up)

typedef __attribute__((ext_vector_type(8))) _Float16 f16x8;
typedef __attribute__((ext_vector_type(4))) _Float16 f16x4;
typedef __attribute__((ext_vector_type(4))) float f32x4;

// ---------------- ws layout (bytes) ----------------
#define WS_CNT   0          // int cnt[8]
#define WS_OFFSP 32         // int offsP[9] (padded cumsum; offsP[8]=totalP)
#define WS_TK    128        // int tk[2048] (i0<<3|i1)
#define WS_GT    8320       // float2 gates[2048]
#define WS_STAT  24704      // float stats[512][10]
#define WS_M1    45184      // float M1[512][8]
#define WS_QV    61568
#define WS_CB    61600
#define WS_LIST  61664      // int list[8][2048]
#define WS_GLIST 127200     // float glist[8][2048]
#define WS_SEL   192736     // int sel[2048*2] (pos per token-k)
#define WS_XF    262144     // fp16 x [2048][512]          (2 MB)
#define WS_W1F   2359296    // fp16 W1^T [8][2048][512]    (16 MB)
#define WS_W2F   19136512   // fp16 W2^T [8][512][2048]    (16 MB)
#define WS_XG    35913728   // fp16 xg [5120][512]         (5 MB)
#define WS_HF    41156608   // fp16 h  [5120][2048]        (20 MB)
#define WS_YB    62128128   // fp16 yb [4][5120][512]      (20 MB)
// end ~83 MB (ws >= 105 MB proven by MFMA path running since R2)

__device__ __forceinline__ float wred(float v) {
#pragma unroll
  for (int o = 32; o > 0; o >>= 1) v += __shfl_down(v, o);
  return v;
}

__device__ __forceinline__ float wredx(float v) {
#pragma unroll
  for (int o = 32; o > 0; o >>= 1) v += __shfl_xor(v, o);
  return v;
}

__device__ __forceinline__ float block_sum(float v, float* s4, int tid) {
  v = wred(v);
  __syncthreads();
  if ((tid & 63) == 0) s4[tid >> 6] = v;
  __syncthreads();
  return s4[0] + s4[1] + s4[2] + s4[3];
}

__device__ __forceinline__ float gelu_f(float v) {
  return 0.5f * v * (1.0f + erff(v * 0.7071067811865475f));
}

#define GL16(gp, lp) __builtin_amdgcn_global_load_lds( \
    (const __attribute__((address_space(1))) void*)(gp), \
    (__attribute__((address_space(3))) void*)(lp), 16, 0, 0)

// ------------------------------------------------------------------
// Merged: precomp (blocks 0..512) + weight transpose/convert (rest).
// ------------------------------------------------------------------
__device__ __forceinline__ void convT_tile(const float* __restrict__ src,
    _Float16* __restrict__ dst, int R, int C, int bx, float* ls) {
  int nr = R >> 6, ncc = C >> 6;
  int e = bx / (nr * ncc);
  int rem = bx % (nr * ncc);
  int rt = rem / ncc, ct = rem % ncc;
  int tid = threadIdx.x;
  const float* s0 = src + (size_t)e * R * C + (size_t)(rt * 64) * C + ct * 64;
#pragma unroll
  for (int j = 0; j < 4; j++) {
    int li = j * 256 + tid;
    int rr = li >> 4, c4 = (li & 15) << 2;
    float4 v = *(const float4*)(s0 + (size_t)rr * C + c4);
    ls[rr * 65 + c4] = v.x;
    ls[rr * 65 + c4 + 1] = v.y;
    ls[rr * 65 + c4 + 2] = v.z;
    ls[rr * 65 + c4 + 3] = v.w;
  }
  __syncthreads();
#pragma unroll
  for (int j = 0; j < 4; j++) {
    int li = j * 256 + tid;
    int on = li >> 4, k4 = (li & 15) << 2;
    f16x4 o;
    o[0] = (_Float16)ls[(k4 + 0) * 65 + on];
    o[1] = (_Float16)ls[(k4 + 1) * 65 + on];
    o[2] = (_Float16)ls[(k4 + 2) * 65 + on];
    o[3] = (_Float16)ls[(k4 + 3) * 65 + on];
    *(f16x4*)(dst + ((size_t)e * C + ct * 64 + on) * R + rt * 64 + k4) = o;
  }
}

__global__ __launch_bounds__(256) void k_pre(
    const float* __restrict__ ctx_W, const float* __restrict__ rtr_W,
    const float* __restrict__ rtr_b, const float* __restrict__ qual_W,
    const float* __restrict__ qual_b, const float* __restrict__ ctx_b,
    const float* __restrict__ W1, const float* __restrict__ W2,
    float* __restrict__ M1, float* __restrict__ qv, float* __restrict__ cb,
    _Float16* __restrict__ w1f, _Float16* __restrict__ w2f) {
  __shared__ float ls[64 * 65];
  int bx = blockIdx.x;
  if (bx >= 513) {
    int cx = bx - 513;
    if (cx < Ee * 8 * 32) convT_tile(W1, w1f, Dd, Hh, cx, ls);
    else convT_tile(W2, w2f, Hh, Dd, cx - Ee * 8 * 32, ls);
    return;
  }
  int d = bx;
  int tid = threadIdx.x;
  if (tid >= 64) return;
  int lane = tid;
  if (d < Dd) {
    float acc[Ee] = {0.f, 0.f, 0.f, 0.f, 0.f, 0.f, 0.f, 0.f};
    for (int k = lane; k < Dd; k += 64) {
      float cw = ctx_W[d * Dd + k];
      const float* r = rtr_W + k * Ee;
#pragma unroll
      for (int e = 0; e < Ee; e++) acc[e] += cw * r[e];
    }
#pragma unroll
    for (int e = 0; e < Ee; e++) acc[e] = wred(acc[e]);
    if (lane == 0) {
#pragma unroll
      for (int e = 0; e < Ee; e++) M1[d * Ee + e] = acc[e];
    }
  } else {
    float aq[Ee] = {0.f, 0.f, 0.f, 0.f, 0.f, 0.f, 0.f, 0.f};
    float ab[Ee] = {0.f, 0.f, 0.f, 0.f, 0.f, 0.f, 0.f, 0.f};
    for (int k = lane; k < Dd; k += 64) {
      float qw = qual_W[k];
      float bb = ctx_b[k] + qual_b[k];
      const float* r = rtr_W + k * Ee;
#pragma unroll
      for (int e = 0; e < Ee; e++) {
        aq[e] += qw * r[e];
        ab[e] += bb * r[e];
      }
    }
#pragma unroll
    for (int e = 0; e < Ee; e++) {
      aq[e] = wred(aq[e]);
      ab[e] = wred(ab[e]);
    }
    if (lane == 0) {
#pragma unroll
      for (int e = 0; e < Ee; e++) {
        qv[e] = aq[e];
        cb[e] = ab[e] + rtr_b[e];
      }
    }
  }
}

// ------------------------------------------------------------------
// Logits + x->fp16 + per-token router math (top2/gates/stats).
// One wave per token; per-block partial stats -> stats[bid][10].
// ------------------------------------------------------------------
__global__ __launch_bounds__(256) void k_logits(
    const float* __restrict__ x, const float* __restrict__ ctx,
    const float* __restrict__ quality, const float* __restrict__ rn_g,
    const float* __restrict__ rn_b, const float* __restrict__ cn_g,
    const float* __restrict__ cn_b, const float* __restrict__ rtr_W,
    const float* __restrict__ M1, const float* __restrict__ qv,
    const float* __restrict__ cb, const float* __restrict__ temperature,
    _Float16* __restrict__ xf, int* __restrict__ tk,
    float2* __restrict__ gates, float* __restrict__ stats) {
  __shared__ float sst[4][10];
  int wid = threadIdx.x >> 6, lane = threadIdx.x & 63;
  int t = blockIdx.x * 4 + wid;
  int d0 = lane * 8;

  float xv[8], cv[8];
  *(float4*)&xv[0] = *(const float4*)(x + (size_t)t * Dd + d0);
  *(float4*)&xv[4] = *(const float4*)(x + (size_t)t * Dd + d0 + 4);
  *(float4*)&cv[0] = *(const float4*)(ctx + (size_t)t * Dd + d0);
  *(float4*)&cv[4] = *(const float4*)(ctx + (size_t)t * Dd + d0 + 4);

  f16x8 xh;
#pragma unroll
  for (int d = 0; d < 8; d++) xh[d] = (_Float16)xv[d];
  *(f16x8*)(xf + (size_t)t * Dd + d0) = xh;

  float sx = 0.f, sc = 0.f;
#pragma unroll
  for (int d = 0; d < 8; d++) { sx += xv[d]; sc += cv[d]; }
  float mx = wredx(sx) * (1.f / Dd);
  float mc = wredx(sc) * (1.f / Dd);
  float vx = 0.f, vc = 0.f;
#pragma unroll
  for (int d = 0; d < 8; d++) {
    vx += (xv[d] - mx) * (xv[d] - mx);
    vc += (cv[d] - mc) * (cv[d] - mc);
  }
  float rsx = rsqrtf(wredx(vx) * (1.f / Dd) + 1e-5f);
  float rsc = rsqrtf(wredx(vc) * (1.f / Dd) + 1e-5f);

  float rg[8], rb[8], cg[8], cbb[8];
  *(float4*)&rg[0] = *(const float4*)(rn_g + d0);
  *(float4*)&rg[4] = *(const float4*)(rn_g + d0 + 4);
  *(float4*)&rb[0] = *(const float4*)(rn_b + d0);
  *(float4*)&rb[4] = *(const float4*)(rn_b + d0 + 4);
  *(float4*)&cg[0] = *(const float4*)(cn_g + d0);
  *(float4*)&cg[4] = *(const float4*)(cn_g + d0 + 4);
  *(float4*)&cbb[0] = *(const float4*)(cn_b + d0);
  *(float4*)&cbb[4] = *(const float4*)(cn_b + d0 + 4);

  float lg[Ee] = {0.f, 0.f, 0.f, 0.f, 0.f, 0.f, 0.f, 0.f};
#pragma unroll
  for (int d = 0; d < 8; d++) {
    float xn = (xv[d] - mx) * rsx * rg[d] + rb[d];
    float cn = (cv[d] - mc) * rsc * cg[d] + cbb[d];
    float rw[8], m1[8];
    *(float4*)&rw[0] = *(const float4*)(rtr_W + (size_t)(d0 + d) * Ee);
    *(float4*)&rw[4] = *(const float4*)(rtr_W + (size_t)(d0 + d) * Ee + 4);
    *(float4*)&m1[0] = *(const float4*)(M1 + (size_t)(d0 + d) * Ee);
    *(float4*)&m1[4] = *(const float4*)(M1 + (size_t)(d0 + d) * Ee + 4);
#pragma unroll
    for (int e = 0; e < Ee; e++) lg[e] += xn * rw[e] + cn * m1[e];
  }
#pragma unroll
  for (int e = 0; e < Ee; e++) lg[e] = wredx(lg[e]);

  if (lane == 0) {
    float invT = 1.f / fmaxf(temperature[0], 0.25f);
    float q = quality[t / Ss];
    float L[8];
#pragma unroll
    for (int e = 0; e < Ee; e++) L[e] = (lg[e] + q * qv[e] + cb[e]) * invT;

    int i0 = 0;
#pragma unroll
    for (int e = 1; e < Ee; e++)
      if (L[e] > L[i0]) i0 = e;
    int i1 = (i0 == 0) ? 1 : 0;
#pragma unroll
    for (int e = 0; e < Ee; e++)
      if (e != i0 && L[e] > L[i1]) i1 = e;

    float e1 = __expf(L[i1] - L[i0]);
    float g0 = 1.f / (1.f + e1);
    float g1 = e1 / (1.f + e1);
    tk[t] = (i0 << 3) | i1;
    gates[t] = make_float2(g0, g1);

    float m = L[i0];
    float p[8];
    float sum = 0.f;
#pragma unroll
    for (int e = 0; e < Ee; e++) {
      p[e] = __expf(L[e] - m);
      sum += p[e];
    }
    float lse = m + __logf(sum);
    float inv = 1.f / sum;
    float ent = 0.f;
#pragma unroll
    for (int e = 0; e < Ee; e++) {
      p[e] *= inv;
      ent -= p[e] * __logf(fmaxf(p[e], 1e-9f));
      sst[wid][e] = p[e];
    }
    sst[wid][8] = lse * lse;
    sst[wid][9] = ent;
  }
  __syncthreads();
  int tid = threadIdx.x;
  if (tid < 10)
    stats[blockIdx.x * 10 + tid] =
        sst[0][tid] + sst[1][tid] + sst[2][tid] + sst[3][tid];
}

// ------------------------------------------------------------------
// Select: ONE block. Slot assignment (LDS atomics) + padded offsets +
// stats reduction + aux scalars. No softmax math (moved to k_logits).
// ------------------------------------------------------------------
__global__ __launch_bounds__(256) void k_select(
    const int* __restrict__ tk, const float2* __restrict__ gates,
    const float* __restrict__ stats, int* __restrict__ cnt,
    int* __restrict__ offsP, int* __restrict__ list,
    float* __restrict__ glist, int* __restrict__ sel,
    float* __restrict__ out) {
  __shared__ int scnt[Ee];
  __shared__ float s4[4];
  int tid = threadIdx.x;
  if (tid < Ee) scnt[tid] = 0;
  __syncthreads();

#pragma unroll
  for (int j = 0; j < 8; j++) {
    int t = j * 256 + tid;
    int pk = tk[t];
    int i0 = (pk >> 3) & 7, i1 = pk & 7;
    float2 g = gates[t];
    int s0 = atomicAdd(&scnt[i0], 1);
    list[i0 * CAP + s0] = t;
    glist[i0 * CAP + s0] = g.x;
    sel[t * 2 + 0] = (i0 << 12) | s0;
    int s1 = atomicAdd(&scnt[i1], 1);
    list[i1 * CAP + s1] = t;
    glist[i1 * CAP + s1] = g.y;
    sel[t * 2 + 1] = (i1 << 12) | s1;
  }
  __syncthreads();

  // stats reduction: 512 blocks x 10
  float rc[10];
#pragma unroll
  for (int c = 0; c < 10; c++)
    rc[c] = stats[tid * 10 + c] + stats[(tid + 256) * 10 + c];
  float rs[10];
#pragma unroll
  for (int c = 0; c < 10; c++) rs[c] = block_sum(rc[c], s4, tid);

  if (tid == 0) {
    int s = 0;
#pragma unroll
    for (int e = 0; e < Ee; e++) {
      cnt[e] = scnt[e];
      offsP[e] = s;
      s += ((scnt[e] + 127) >> 7) << 7;   // pad to 128
    }
    offsP[Ee] = s;

    float lb = 0.f;
#pragma unroll
    for (int e = 0; e < Ee; e++) {
      float v = rs[e] * (1.f / TOKENS) - (1.f / Ee);
      lb += v * v;
    }
    lb *= (1.f / Ee);
    float rz = rs[8] * (1.f / TOKENS);
    float en = rs[9] * (1.f / TOKENS);
    float* sp = out + (size_t)Bb * Ss * Dd;
    sp[0] = lb;
    sp[1] = rz;
    sp[2] = en;
    sp[3] = lb + 0.001f * rz - 0.001f * en;
  }
}

// ------------------------------------------------------------------
// Gather: xg[slot] = xf[list[slot]] (zeros for pad slots).
// One wave per slot. grid: SLOTS/4 x 256
// ------------------------------------------------------------------
__global__ __launch_bounds__(256) void k_gather(
    const _Float16* __restrict__ xf, const int* __restrict__ cnt,
    const int* __restrict__ offsP, const int* __restrict__ list,
    _Float16* __restrict__ xg) {
  int s = blockIdx.x * 4 + (threadIdx.x >> 6);
  int lane = threadIdx.x & 63;
  int e = 0;
#pragma unroll
  for (int q = 0; q < 7; q++)
    if (s >= offsP[q + 1]) e = q + 1;
  int pos = s - offsP[e];
  f16x8 v = {};
  if (s < offsP[Ee] && pos < cnt[e]) {
    int t = list[e * CAP + pos];
    v = *(const f16x8*)(xf + (size_t)t * Dd + lane * 8);
  }
  *(f16x8*)(xg + (size_t)s * Dd + lane * 8) = v;
}

// ------------------------------------------------------------------
// GEMM1 fp16: xg (slot-compact) @ W1[e] (512 x 2048), gelu -> hf
// 128x128 tile, BK=64, dense slot grid. grid: 40r x 16c
// ------------------------------------------------------------------
__global__ __launch_bounds__(256) void k_mg1(
    const _Float16* __restrict__ xg, const _Float16* __restrict__ w1f,
    const float* __restrict__ b1, const int* __restrict__ offsP,
    _Float16* __restrict__ hf) {
  int bx = blockIdx.x;
  int r = bx >> 4;
  int c = bx & 15;
  int totalP = offsP[Ee];
  if (r * 128 >= totalP) return;
  int e = 0;
#pragma unroll
  for (int q = 0; q < 7; q++)
    if (r * 128 >= offsP[q + 1]) e = q + 1;

  __shared__ _Float16 As[8 * 128 * 8];   // 16 KB
  __shared__ _Float16 Bs[8 * 128 * 8];   // 16 KB

  int tid = threadIdx.x;
  size_t asrc[4], bsrc[4];
  int lq[4];
#pragma unroll
  for (int q = 0; q < 4; q++) {
    int idx = q * 256 + tid;
    int g = idx >> 7, row = idx & 127;
    asrc[q] = (size_t)(r * 128 + row) * Dd + g * 8;
    bsrc[q] = ((size_t)(e * Hh + c * 128 + row)) * Dd + g * 8;
    lq[q] = idx * 8;
  }

  int lane = tid & 63, wid = tid >> 6;
  int wm = wid >> 1, wn = wid & 1;
  int l15 = lane & 15, lg = lane >> 4;

  f32x4 acc[4][4] = {};

  for (int k0 = 0; k0 < Dd; k0 += 64) {
#pragma unroll
    for (int q = 0; q < 4; q++) {
      GL16(xg + asrc[q] + k0, &As[lq[q]]);
      GL16(w1f + bsrc[q] + k0, &Bs[lq[q]]);
    }
    __syncthreads();
    f16x8 a[2][4], b[2][4];
#pragma unroll
    for (int ks = 0; ks < 2; ks++) {
#pragma unroll
      for (int m = 0; m < 4; m++)
        a[ks][m] = *(const f16x8*)&As[(((ks * 4 + lg) << 7) + wm * 64 + m * 16 + l15) * 8];
#pragma unroll
      for (int n = 0; n < 4; n++)
        b[ks][n] = *(const f16x8*)&Bs[(((ks * 4 + lg) << 7) + wn * 64 + n * 16 + l15) * 8];
    }
#pragma unroll
    for (int ks = 0; ks < 2; ks++)
#pragma unroll
      for (int m = 0; m < 4; m++)
#pragma unroll
        for (int n = 0; n < 4; n++)
          acc[m][n] = __builtin_amdgcn_mfma_f32_16x16x32_f16(a[ks][m], b[ks][n], acc[m][n], 0, 0, 0);
    __syncthreads();
  }

  int lg4 = lg * 4;
#pragma unroll
  for (int n = 0; n < 4; n++) {
    int colg = c * 128 + wn * 64 + n * 16 + l15;
    float bias = b1[e * Hh + colg];
#pragma unroll
    for (int m = 0; m < 4; m++) {
#pragma unroll
      for (int j = 0; j < 4; j++) {
        int rowl = r * 128 + wm * 64 + m * 16 + lg4 + j;
        hf[(size_t)rowl * Hh + colg] = (_Float16)gelu_f(acc[m][n][j] + bias);
      }
    }
  }
}

// ------------------------------------------------------------------
// GEMM2 fp16: hf (slot-compact) @ W2[e], split-K=4, fp16 partials -> yb.
// grid: 40r x 4c x 4k
// ------------------------------------------------------------------
__global__ __launch_bounds__(256) void k_mg2(
    const _Float16* __restrict__ hf, const _Float16* __restrict__ w2f,
    const int* __restrict__ offsP, _Float16* __restrict__ yb) {
  int bx = blockIdx.x;
  int r = bx >> 4;
  int c = (bx >> 2) & 3;
  int kS = bx & 3;
  int totalP = offsP[Ee];
  if (r * 128 >= totalP) return;
  int e = 0;
#pragma unroll
  for (int q = 0; q < 7; q++)
    if (r * 128 >= offsP[q + 1]) e = q + 1;

  __shared__ _Float16 As[8 * 128 * 8];
  __shared__ _Float16 Bs[8 * 128 * 8];

  int tid = threadIdx.x;
  size_t kbase = (size_t)kS * 512;

  size_t asrc[4], bsrc[4];
  int lq[4];
#pragma unroll
  for (int q = 0; q < 4; q++) {
    int idx = q * 256 + tid;
    int g = idx >> 7, row = idx & 127;
    asrc[q] = (size_t)(r * 128 + row) * Hh + kbase + g * 8;
    bsrc[q] = ((size_t)(e * Dd + c * 128 + row)) * Hh + kbase + g * 8;
    lq[q] = idx * 8;
  }

  int lane = tid & 63, wid = tid >> 6;
  int wm = wid >> 1, wn = wid & 1;
  int l15 = lane & 15, lg = lane >> 4;

  f32x4 acc[4][4] = {};

  for (int k0 = 0; k0 < 512; k0 += 64) {
#pragma unroll
    for (int q = 0; q < 4; q++) {
      GL16(hf + asrc[q] + k0, &As[lq[q]]);
      GL16(w2f + bsrc[q] + k0, &Bs[lq[q]]);
    }
    __syncthreads();
    f16x8 a[2][4], b[2][4];
#pragma unroll
    for (int ks = 0; ks < 2; ks++) {
#pragma unroll
      for (int m = 0; m < 4; m++)
        a[ks][m] = *(const f16x8*)&As[(((ks * 4 + lg) << 7) + wm * 64 + m * 16 + l15) * 8];
#pragma unroll
      for (int n = 0; n < 4; n++)
        b[ks][n] = *(const f16x8*)&Bs[(((ks * 4 + lg) << 7) + wn * 64 + n * 16 + l15) * 8];
    }
#pragma unroll
    for (int ks = 0; ks < 2; ks++)
#pragma unroll
      for (int m = 0; m < 4; m++)
#pragma unroll
        for (int n = 0; n < 4; n++)
          acc[m][n] = __builtin_amdgcn_mfma_f32_16x16x32_f16(a[ks][m], b[ks][n], acc[m][n], 0, 0, 0);
    __syncthreads();
  }

  int lg4 = lg * 4;
#pragma unroll
  for (int m = 0; m < 4; m++) {
#pragma unroll
    for (int j = 0; j < 4; j++) {
      int rowl = r * 128 + wm * 64 + m * 16 + lg4 + j;
      _Float16* yp = yb + ((size_t)kS * SLOTS + rowl) * Dd;
#pragma unroll
      for (int n = 0; n < 4; n++) {
        int colg = c * 128 + wn * 64 + n * 16 + l15;
        yp[colg] = (_Float16)acc[m][n][j];
      }
    }
  }
}

// ------------------------------------------------------------------
// Combine: out[t] = sum_k gate_k * (sum_s yb[s][slotP_k] + b2[e_k]).
// ------------------------------------------------------------------
__global__ __launch_bounds__(256) void k_comb(
    const _Float16* __restrict__ yb, const int* __restrict__ sel,
    const float* __restrict__ glist, const int* __restrict__ offsP,
    const float* __restrict__ b2, float* __restrict__ out) {
  int t = blockIdx.x * 4 + (threadIdx.x >> 6);
  int lane = threadIdx.x & 63;
  int c0 = lane * 8;

  float acc[8] = {0.f, 0.f, 0.f, 0.f, 0.f, 0.f, 0.f, 0.f};
#pragma unroll
  for (int k = 0; k < 2; k++) {
    int pk = sel[t * 2 + k];
    int e = pk >> 12, pos = pk & 4095;
    int slot = offsP[e] + pos;
    float g = glist[e * CAP + pos];
    float pa[8] = {0.f, 0.f, 0.f, 0.f, 0.f, 0.f, 0.f, 0.f};
#pragma unroll
    for (int s = 0; s < 4; s++) {
      f16x8 v = *(const f16x8*)(yb + ((size_t)s * SLOTS + slot) * Dd + c0);
#pragma unroll
      for (int j = 0; j < 8; j++) pa[j] += (float)v[j];
    }
    const float* bb = b2 + e * Dd + c0;
    float b4[8];
    *(float4*)&b4[0] = *(const float4*)bb;
    *(float4*)&b4[4] = *(const float4*)(bb + 4);
#pragma unroll
    for (int j = 0; j < 8; j++) acc[j] += g * (pa[j] + b4[j]);
  }
  float* op = out + (size_t)t * Dd + c0;
  *(float4*)op = *(float4*)&acc[0];
  *(float4*)(op + 4) = *(float4*)&acc[4];
}

extern "C" void kernel_launch(void* const* d_in, const int* in_sizes, int n_in,
                              void* d_out, int out_size, void* d_ws, size_t ws_size,
                              hipStream_t stream) {
  const float* x = (const float*)d_in[0];
  const float* ctx = (const float*)d_in[1];
  const float* quality = (const float*)d_in[2];
  const float* rn_g = (const float*)d_in[3];
  const float* rn_b = (const float*)d_in[4];
  const float* cn_g = (const float*)d_in[5];
  const float* cn_b = (const float*)d_in[6];
  const float* ctx_W = (const float*)d_in[7];
  const float* ctx_b = (const float*)d_in[8];
  const float* qual_W = (const float*)d_in[9];
  const float* qual_b = (const float*)d_in[10];
  const float* rtr_W = (const float*)d_in[11];
  const float* rtr_b = (const float*)d_in[12];
  const float* temperature = (const float*)d_in[13];
  const float* W1 = (const float*)d_in[14];
  const float* b1 = (const float*)d_in[15];
  const float* W2 = (const float*)d_in[16];
  const float* b2 = (const float*)d_in[17];
  float* out = (float*)d_out;

  char* w = (char*)d_ws;
  int* cnt = (int*)(w + WS_CNT);
  int* offsP = (int*)(w + WS_OFFSP);
  int* tk = (int*)(w + WS_TK);
  float2* gates = (float2*)(w + WS_GT);
  float* stats = (float*)(w + WS_STAT);
  float* M1 = (float*)(w + WS_M1);
  float* qv = (float*)(w + WS_QV);
  float* cb = (float*)(w + WS_CB);
  int* list = (int*)(w + WS_LIST);
  float* glist = (float*)(w + WS_GLIST);
  int* sel = (int*)(w + WS_SEL);
  _Float16* xf = (_Float16*)(w + WS_XF);
  _Float16* w1f = (_Float16*)(w + WS_W1F);
  _Float16* w2f = (_Float16*)(w + WS_W2F);
  _Float16* xg = (_Float16*)(w + WS_XG);
  _Float16* hf = (_Float16*)(w + WS_HF);
  _Float16* yb = (_Float16*)(w + WS_YB);

  k_pre<<<513 + Ee * 8 * 32 * 2, 256, 0, stream>>>(
      ctx_W, rtr_W, rtr_b, qual_W, qual_b, ctx_b, W1, W2, M1, qv, cb, w1f, w2f);
  k_logits<<<TOKENS / 4, 256, 0, stream>>>(x, ctx, quality, rn_g, rn_b, cn_g, cn_b, rtr_W,
                                           M1, qv, cb, temperature, xf, tk, gates, stats);
  k_select<<<1, 256, 0, stream>>>(tk, gates, stats, cnt, offsP, list, glist, sel, out);
  k_gather<<<SLOTS / 4, 256, 0, stream>>>(xf, cnt, offsP, list, xg);
  k_mg1<<<40 * 16, 256, 0, stream>>>(xg, w1f, b1, offsP, hf);
  k_mg2<<<40 * 4 * 4, 256, 0, stream>>>(hf, w2f, offsP, yb);
  k_comb<<<TOKENS / 4, 256, 0, stream>>>(yb, sel, glist, offsP, b2, out);
}